// Round 7
// baseline (204.425 us; speedup 1.0000x reference)
//
#include <hip/hip_runtime.h>

// Fused ISTFT as one MFMA GEMM, j-major K layout:
//   out[(b,g)][n] = ( sum_{k''} A[m'][k''] * Bfold[k''][n] ) / wsum[n]
// k'' = j*1088 + c; c<544: re[kk=c], else im[kk=c-544] (valid kk<513, zero-pad).
// A-image (LINEAR bf16, rows f = b*2048 + t, 1088 elems = 2176 B):
//   row f = [ re[f][0..512], 0 pad .. 543, im[f][0..512], 0 pad .. 1087 ]
// Bfold[j*1088+c][n] = f(kk)*Wr[kk][n+256j] / -f(kk)*Wi[kk][n+256j], f=2 except DC/Nyq.
// out flat = (b*2047+gi)*256 + n.
//
// Round 7: same as round 6 (A direct-to-reg, B via gload_lds depth-3) but with
// A-prefetch depth 2 (3 named reg sets, unroll-3) and 3 blocks/CU — round 6's
// regression was exposed A-load latency (depth-1 prefetch), not the reg-A idea.

#define BATCH    8
#define NFRAMES  2048
#define FREQ     513
#define NFFT     1024
#define OUTCOLS  524032
#define NKT      68            // K'' = 4352 = 68*64
#define APITCH   2176          // bytes per A-image row (1088 bf16)
#define BSB      (NKT * 32768) // 2,228,224 B (68 tiles x 2 halves x 16KB)
#define GUARDB   (64 * APITCH)
#define AIMG_OFF ((size_t)BSB + GUARDB)
#define WS_NEED  (AIMG_OFF + (size_t)16384 * APITCH + GUARDB)

#define PA_BLOCKS 4352         // 4352*256 = 16384*68 (16-elem groups)
#define PB_BLOCKS 2176         // 2176*256 = 136*4096 dwords

typedef __attribute__((ext_vector_type(8))) short bf16x8;
typedef __attribute__((ext_vector_type(4))) float f32x4;

__device__ __forceinline__ unsigned short f2bf(float x) {
    unsigned u = __float_as_uint(x);
    return (unsigned short)((u + 0x7fffu + ((u >> 16) & 1u)) >> 16);
}

// ============ merged prep: linear A transcode + swizzled B build ============
__global__ __launch_bounds__(256) void prep_AB(const float* __restrict__ re,
                                               const float* __restrict__ im,
                                               const float* __restrict__ Wr,
                                               const float* __restrict__ Wi,
                                               char* __restrict__ ws) {
    const int bx = blockIdx.x;
    if (bx < PA_BLOCKS) {
        // ---- A: linear bf16 image, 16 elems (32B) per thread ----
        unsigned gid = (unsigned)bx * 256u + threadIdx.x;
        unsigned row = gid / 68u;
        int g16 = (int)(gid - row * 68u);
        const float* src = (g16 < 34) ? (re + (size_t)row * FREQ) : (im + (size_t)row * FREQ);
        const int cbase = (g16 < 34) ? g16 * 16 : (g16 - 34) * 16;
        bf16x8 v0, v1;
#pragma unroll
        for (int e = 0; e < 8; ++e) {
            int c = cbase + e;
            v0[e] = (short)((c < FREQ) ? f2bf(src[c]) : 0);
        }
#pragma unroll
        for (int e = 0; e < 8; ++e) {
            int c = cbase + 8 + e;
            v1[e] = (short)((c < FREQ) ? f2bf(src[c]) : 0);
        }
        char* dst = ws + AIMG_OFF + (size_t)row * APITCH + g16 * 32;
        *(bf16x8*)dst = v0;
        *(bf16x8*)(dst + 16) = v1;
    } else {
        // ---- B: 68 tiles x 2 halves x [128 nn][64 k], XOR-pre-swizzled ----
        int id = (bx - PA_BLOCKS) * 256 + threadIdx.x;
        int hid  = id >> 12;        // kt*2+nh (0..135)
        int rem  = id & 4095;
        int nn   = rem >> 5;        // 0..127
        int dstd = rem & 31;        // stored dword-in-row
        int dsrc = dstd ^ ((nn & 7) << 2);
        int kt = hid >> 1, nh = hid & 1;
        int kg = kt * 64 + dsrc * 2;
        int j  = kg / 1088;
        int c  = kg - j * 1088;
        int col = nh * 128 + nn + 256 * j;
        unsigned short h[2];
#pragma unroll
        for (int e = 0; e < 2; ++e) {
            int ce = c + e;
            float v = 0.0f;
            if (ce < 544) {
                if (ce < FREQ) {
                    float f = (ce == 0 || ce == FREQ - 1) ? 1.0f : 2.0f;
                    v = f * Wr[(size_t)ce * NFFT + col];
                }
            } else {
                int ci = ce - 544;
                if (ci < FREQ) {
                    float f = (ci == 0 || ci == FREQ - 1) ? 1.0f : 2.0f;
                    v = -f * Wi[(size_t)ci * NFFT + col];
                }
            }
            h[e] = f2bf(v);
        }
        unsigned d = (unsigned)h[0] | ((unsigned)h[1] << 16);
        *(unsigned*)(ws + (size_t)hid * 16384 + nn * 128 + dstd * 4) = d;
    }
}

// ============ main: BM=64 x BN=128, A reg-prefetch depth-2, B LDS depth-3 ============
__global__ __launch_bounds__(256, 3) void istft_mfma7(
    const char* __restrict__ ws_c, const float* __restrict__ ola,
    float* __restrict__ out) {
    __shared__ __attribute__((aligned(16))) unsigned short Bbuf[3][128][64]; // 48KB
    __shared__ float s_wsum[256], s_ola0[256], s_ola3[256];

    const int tid = threadIdx.x;
    const int l   = tid & 63;
    const int w   = tid >> 6;   // 0..3 = N quarter (wave tile 64x32)

    // XCD-bijective swizzle (512 = 8*64): nh pairs adjacent on same XCD
    const int bx  = blockIdx.x;
    const int sid = (bx & 7) * 64 + (bx >> 3);
    const int mt  = sid >> 1;   // 0..255
    const int nh  = sid & 1;

    const char* Aimg = ws_c + AIMG_OFF;
    const char* Bimg = ws_c;

    {
        float o0 = ola[tid], o1 = ola[tid + 256], o2 = ola[tid + 512], o3 = ola[tid + 768];
        s_wsum[tid] = o0 + o1 + o2 + o3;
        s_ola0[tid] = o0;
        s_ola3[tid] = o3;
    }

    const int b_  = (mt * 64) >> 11;        // batch (uniform per block)
    const int gi0 = (mt * 64) & 2047;
    const bool edge_lo = (gi0 == 0);
    const bool edge_hi = (gi0 == 1984);

    // per-lane A-frag base: row t = gi0 + 2 + (l&15) at j=0,mb=0; k-elem (l>>4)*8
    const char* abase = Aimg + (size_t)(b_ * 2048 + gi0 + 2 + (l & 15)) * APITCH
                      + ((l >> 4) << 4);

    f32x4 acc[4][2];
#pragma unroll
    for (int i = 0; i < 4; ++i)
#pragma unroll
        for (int n = 0; n < 2; ++n) acc[i][n] = (f32x4){0.f, 0.f, 0.f, 0.f};

    bf16x8 aS0[4][2], aS1[4][2], aS2[4][2];   // rotation-3 A-frag sets
    const bf16x8 z8 = (bf16x8){0,0,0,0,0,0,0,0};

    int jn = 0, ktn = 0;                      // j/ktm of the NEXT tile to A-load

    auto LOAD_A = [&](bf16x8 (&aN)[4][2]) {
        const char* p = abase + (ptrdiff_t)ktn * 128 - (ptrdiff_t)jn * APITCH;
#pragma unroll
        for (int mb = 0; mb < 4; ++mb) {
            aN[mb][0] = *(const bf16x8*)(p + mb * 34816);
            aN[mb][1] = *(const bf16x8*)(p + mb * 34816 + 64);
        }
        if (edge_lo && jn == 3 && (l & 15) == 0) { aN[0][0] = z8; aN[0][1] = z8; }
        if (edge_hi) {
            if (jn == 0 && (l & 15) >= 14) { aN[3][0] = z8; aN[3][1] = z8; }
            if (jn == 1 && (l & 15) == 15) { aN[3][0] = z8; aN[3][1] = z8; }
        }
        if (++ktn == 17) { ktn = 0; ++jn; }
    };

    auto STAGE_B = [&](int kt, int buf) {
        const char* bsrc = Bimg + (size_t)(kt * 2 + nh) * 16384 + (size_t)tid * 16;
        char* bdst = (char*)&Bbuf[buf][0][0] + w * 1024;  // wave-uniform; HW adds lane*16
#pragma unroll
        for (int c = 0; c < 4; ++c)
            __builtin_amdgcn_global_load_lds(
                (const __attribute__((address_space(1))) unsigned*)(bsrc + c * 4096),
                (__attribute__((address_space(3))) unsigned*)(bdst + c * 4096), 16, 0, 0);
    };

    auto COMPUTE = [&](int buf, bf16x8 (&aC)[4][2]) {
        const char* Bb = (const char*)&Bbuf[buf][0][0];
#pragma unroll
        for (int ks = 0; ks < 2; ++ks) {
            const int grpK = ks * 4 + (l >> 4);
            bf16x8 bfr[2];
#pragma unroll
            for (int nb = 0; nb < 2; ++nb) {
                int nn = w * 32 + nb * 16 + (l & 15);
                bfr[nb] = *(const bf16x8*)(Bb + nn * 128 + ((grpK ^ (nn & 7)) << 4));
            }
            __builtin_amdgcn_s_setprio(1);
#pragma unroll
            for (int mb = 0; mb < 4; ++mb)
#pragma unroll
                for (int nb = 0; nb < 2; ++nb)
                    acc[mb][nb] = __builtin_amdgcn_mfma_f32_16x16x32_bf16(aC[mb][ks], bfr[nb], acc[mb][nb], 0, 0, 0);
            __builtin_amdgcn_s_setprio(0);
        }
    };

    // ---- prologue: tiles 0,1 fully in flight (B->LDS, A->regs) ----
    STAGE_B(0, 0);
    LOAD_A(aS0);
    STAGE_B(1, 1);
    LOAD_A(aS1);

    // ---- main loop: unroll-3 over rotation of named A-sets ----
    // Per BODY: 12 vmem issues (4 B + 8 A). Steady wait vmcnt(24) = 2 bodies
    // in flight -> tile i's A+B (issued 2 bodies ago) retired. Tail: 12, 0.
#define BODY(I, ACUR, APRE)                                                    \
    {                                                                          \
        const int rem = NKT - (I);                                             \
        if (rem > 2) { STAGE_B((I) + 2, ((I) + 2) % 3); LOAD_A(APRE); }        \
        if (rem > 2)      { asm volatile("s_waitcnt vmcnt(24)" ::: "memory"); }\
        else if (rem == 2){ asm volatile("s_waitcnt vmcnt(12)" ::: "memory"); }\
        else              { asm volatile("s_waitcnt vmcnt(0)"  ::: "memory"); }\
        __builtin_amdgcn_s_barrier();                                          \
        __builtin_amdgcn_sched_barrier(0);                                     \
        COMPUTE((I) % 3, ACUR);                                                \
        __builtin_amdgcn_s_barrier();                                          \
        __builtin_amdgcn_sched_barrier(0);                                     \
    }

    for (int i = 0; i < 66; i += 3) {
        BODY(i,     aS0, aS2);
        BODY(i + 1, aS1, aS0);
        BODY(i + 2, aS2, aS1);
    }
    BODY(66, aS0, aS2);   // rem=2: no prefetch
    BODY(67, aS1, aS0);   // rem=1
#undef BODY

    // ---- epilogue: /wsum with edge corrections, direct store ----
#pragma unroll
    for (int mb = 0; mb < 4; ++mb) {
#pragma unroll
        for (int rr = 0; rr < 4; ++rr) {
            int ml = mb * 16 + (l >> 4) * 4 + rr;
            int mg = mt * 64 + ml;
            int bb = mg >> 11;
            int gi = mg & 2047;
            if (gi > 2046) continue;
#pragma unroll
            for (int nb = 0; nb < 2; ++nb) {
                int n = nh * 128 + w * 32 + nb * 16 + (l & 15);
                float wsv = s_wsum[n];
                if (gi == 0)    wsv -= s_ola3[n];
                if (gi == 2046) wsv -= s_ola0[n];
                wsv = fmaxf(wsv, 1e-11f);
                out[(size_t)(bb * 2047 + gi) * 256 + n] = acc[mb][nb][rr] / wsv;
            }
        }
    }
}

// ---------------- last-resort naive fallback ----------------
__global__ __launch_bounds__(256) void istft_naive(
    const float* __restrict__ re, const float* __restrict__ im,
    const float* __restrict__ Wr, const float* __restrict__ Wi,
    const float* __restrict__ ola, float* __restrict__ out) {
    const int g = blockIdx.x + 2, b = blockIdx.y, ls = threadIdx.x;
    __shared__ float s_fr[4][FREQ];
    __shared__ float s_fi[4][FREQ];
#pragma unroll
    for (int jj = 0; jj < 4; ++jj) {
        const int t = g - jj;
        const bool valid = (t >= 0 && t < NFRAMES);
        const size_t base = ((size_t)b * NFRAMES + (valid ? t : 0)) * FREQ;
        for (int k = ls; k < FREQ; k += 256) {
            const float f = (k == 0 || k == FREQ - 1) ? 1.0f : 2.0f;
            s_fr[jj][k] = valid ? re[base + k] * f : 0.0f;
            s_fi[jj][k] = valid ? im[base + k] * f : 0.0f;
        }
    }
    __syncthreads();
    const float* wr = Wr + ls;
    const float* wi = Wi + ls;
    float acc = 0.0f;
    for (int k = 0; k < FREQ; ++k) {
        const float* wrk = wr + (size_t)k * NFFT;
        const float* wik = wi + (size_t)k * NFFT;
#pragma unroll
        for (int jj = 0; jj < 4; ++jj) {
            acc = fmaf(wrk[jj * 256], s_fr[jj][k], acc);
            acc = fmaf(-wik[jj * 256], s_fi[jj][k], acc);
        }
    }
    float wsv = 0.0f;
#pragma unroll
    for (int jj = 0; jj < 4; ++jj) {
        const int t = g - jj;
        if (t >= 0 && t < NFRAMES) wsv += ola[ls + jj * 256];
    }
    wsv = fmaxf(wsv, 1e-11f);
    out[(size_t)b * OUTCOLS + (g * 256 + ls - 512)] = acc / wsv;
}

extern "C" void kernel_launch(void* const* d_in, const int* in_sizes, int n_in,
                              void* d_out, int out_size, void* d_ws, size_t ws_size,
                              hipStream_t stream) {
    const float* re  = (const float*)d_in[0];
    const float* im  = (const float*)d_in[1];
    const float* Wr  = (const float*)d_in[2];
    const float* Wi  = (const float*)d_in[3];
    const float* ola = (const float*)d_in[4];
    float* out = (float*)d_out;

    if (ws_size >= WS_NEED) {
        char* ws = (char*)d_ws;
        hipLaunchKernelGGL(prep_AB, dim3(PA_BLOCKS + PB_BLOCKS), dim3(256), 0, stream,
                           re, im, Wr, Wi, ws);
        hipLaunchKernelGGL(istft_mfma7, dim3(512), dim3(256), 0, stream, ws, ola, out);
    } else {
        dim3 grid(2047, BATCH);
        hipLaunchKernelGGL(istft_naive, grid, dim3(256), 0, stream, re, im, Wr, Wi, ola, out);
    }
}

// Round 8
// 70.960 us; speedup vs baseline: 2.8808x; 2.8808x over previous
//
#include <hip/hip_runtime.h>

// ISTFT via FFT: frames[b,t,n] = Re{ sum_k X[k] e^{+2pi i kn/1024} } * hann[n]/1024,
// X = hermitian extension of (re + i*im)[b,t,:].  (Identical math to reference's
// W_real/W_imag einsum — cos/sin matrices ARE the inverse DFT * hann / N.)
// Kernel 1: one 1024-pt radix-4 Stockham inverse FFT per (b,t), 256 thr/block,
//           writes bf16 frames to ws.
// Kernel 2: proven round-1 OLA gather: out[b, 256g+ls-512] =
//           sum_j frames[b][g-j][ls+256j] / wsum,  j-validity mask on t=g-j.

#define BATCH    8
#define NFRAMES  2048
#define FREQ     513
#define OUTCOLS  524032
#define WS_NEED  ((size_t)16384 * 1024 * 2)   // 33,554,432 B of bf16 frames

#define PD(a) ((a) + ((a) >> 5))              // +1 float pad per 32 (bank spread)

typedef __attribute__((ext_vector_type(2))) float f32x2;

__device__ __forceinline__ unsigned short f2bf(float x) {
    unsigned u = __float_as_uint(x);
    return (unsigned short)((u + 0x7fffu + ((u >> 16) & 1u)) >> 16);
}

// ================= kernel 1: 1024-pt inverse FFT per (b,t) =================
__global__ __launch_bounds__(256) void ifft_frames(
    const float* __restrict__ re, const float* __restrict__ im,
    const float* __restrict__ ola, unsigned short* __restrict__ frames) {
    __shared__ float xr[1056], xi[1056], yr[1056], yi[1056];
    __shared__ float twr[1024], twi[1024];

    const int row = blockIdx.x;        // b*2048 + t
    const int tid = threadIdx.x;

    // twiddle table: e^{+2pi i k/1024}
    for (int k = tid; k < 1024; k += 256) {
        float s, c;
        sincosf(6.283185307179586f * (float)k * (1.0f / 1024.0f), &s, &c);
        twr[k] = c; twi[k] = s;
    }

    // load spectrum + hermitian mirror: X[1024-k] = conj(X[k]), k=1..511
    const float* fre = re + (size_t)row * FREQ;
    const float* fim = im + (size_t)row * FREQ;
    float a0 = fre[tid],       b0 = fim[tid];        // k = 0..255
    float a1 = fre[tid + 256], b1 = fim[tid + 256];  // k = 256..511
    xr[PD(tid)]       = a0;  xi[PD(tid)]       = b0;
    xr[PD(tid + 256)] = a1;  xi[PD(tid + 256)] = b1;
    if (tid > 0) { xr[PD(1024 - tid)] = a0;  xi[PD(1024 - tid)] = -b0; }  // 769..1023
    xr[PD(768 - tid)] = a1;  xi[PD(768 - tid)] = -b1;                     // 513..768
    if (tid == 0) { xr[PD(512)] = fre[512]; xi[PD(512)] = fim[512]; }
    __syncthreads();

    // radix-4 DIF Stockham, inverse sign (+i twiddles, +i DFT4).
    // stage(S): n = 1024/S; reads r0 = tid + 256k; writes 4*S*p + q + S*k;
    // twiddle idx t1 = p*S (w1), 2*t1 (w2), 3*t1 (w3).
#define STAGE(S, RR, RI, WR, WI)                                              \
    {                                                                         \
        const int p  = tid / (S);                                             \
        const int q  = tid % (S);                                             \
        float ar = RR[PD(tid)],       ai = RI[PD(tid)];                       \
        float br = RR[PD(tid + 256)], bi = RI[PD(tid + 256)];                 \
        float cr = RR[PD(tid + 512)], ci = RI[PD(tid + 512)];                 \
        float dr = RR[PD(tid + 768)], di = RI[PD(tid + 768)];                 \
        float apcr = ar + cr, apci = ai + ci;                                 \
        float amcr = ar - cr, amci = ai - ci;                                 \
        float bpdr = br + dr, bpdi = bi + di;                                 \
        float jbr  = -(bi - di), jbi = (br - dr);   /* i*(b-d) */             \
        const int t1 = p * (S);                                               \
        float w1r = twr[t1],     w1i = twi[t1];                               \
        float w2r = twr[2 * t1], w2i = twi[2 * t1];                           \
        float w3r = twr[3 * t1], w3i = twi[3 * t1];                           \
        const int wb = 4 * (S) * p + q;                                       \
        WR[PD(wb)] = apcr + bpdr;  WI[PD(wb)] = apci + bpdi;                  \
        float u1r = amcr + jbr, u1i = amci + jbi;                             \
        WR[PD(wb + (S))]     = u1r * w1r - u1i * w1i;                         \
        WI[PD(wb + (S))]     = u1r * w1i + u1i * w1r;                         \
        float u2r = apcr - bpdr, u2i = apci - bpdi;                           \
        WR[PD(wb + 2 * (S))] = u2r * w2r - u2i * w2i;                         \
        WI[PD(wb + 2 * (S))] = u2r * w2i + u2i * w2r;                         \
        float u3r = amcr - jbr, u3i = amci - jbi;                             \
        WR[PD(wb + 3 * (S))] = u3r * w3r - u3i * w3i;                         \
        WI[PD(wb + 3 * (S))] = u3r * w3i + u3i * w3r;                         \
        __syncthreads();                                                      \
    }

    STAGE(1,   xr, xi, yr, yi)   // n = 1024
    STAGE(4,   yr, yi, xr, xi)   // n = 256
    STAGE(16,  xr, xi, yr, yi)   // n = 64
    STAGE(64,  yr, yi, xr, xi)   // n = 16
    STAGE(256, xr, xi, yr, yi)   // n = 4   -> result in (yr, yi)
#undef STAGE

    // frames[n] = Re(Y[n]) * hann[n] / 1024, hann = sqrt(ola);  bf16 pack x2.
    const float inv = 1.0f / 1024.0f;
    unsigned* fout = (unsigned*)frames + (size_t)row * 512;
#pragma unroll
    for (int h = 0; h < 2; ++h) {
        int n = 2 * tid + 512 * h;
        f32x2 o = *(const f32x2*)(ola + n);
        float f0 = yr[PD(n)]     * sqrtf(o[0]) * inv;
        float f1 = yr[PD(n + 1)] * sqrtf(o[1]) * inv;
        fout[tid + 256 * h] = (unsigned)f2bf(f0) | ((unsigned)f2bf(f1) << 16);
    }
}

// ================= kernel 2: OLA gather + wsum normalize (round-1 proven) =================
__global__ __launch_bounds__(256) void ola_fold(
    const unsigned short* __restrict__ frames, const float* __restrict__ ola,
    float* __restrict__ out) {
    const int g  = blockIdx.x + 2;   // 2..2048
    const int b  = blockIdx.y;
    const int ls = threadIdx.x;

    float acc = 0.0f, wsv = 0.0f;
#pragma unroll
    for (int j = 0; j < 4; ++j) {
        const int t = g - j;
        if (t >= 0 && t < NFRAMES) {
            unsigned short h = frames[((size_t)(b * NFRAMES + t) << 10) + ls + 256 * j];
            acc += __uint_as_float(((unsigned)h) << 16);
            wsv += ola[ls + 256 * j];
        }
    }
    wsv = fmaxf(wsv, 1e-11f);
    out[(size_t)b * OUTCOLS + (g * 256 + ls - 512)] = acc / wsv;
}

// ================= last-resort naive fallback (round-1, proven) =================
__global__ __launch_bounds__(256) void istft_naive(
    const float* __restrict__ re, const float* __restrict__ im,
    const float* __restrict__ Wr, const float* __restrict__ Wi,
    const float* __restrict__ ola, float* __restrict__ out) {
    const int g = blockIdx.x + 2, b = blockIdx.y, ls = threadIdx.x;
    __shared__ float s_fr[4][FREQ];
    __shared__ float s_fi[4][FREQ];
#pragma unroll
    for (int jj = 0; jj < 4; ++jj) {
        const int t = g - jj;
        const bool valid = (t >= 0 && t < NFRAMES);
        const size_t base = ((size_t)b * NFRAMES + (valid ? t : 0)) * FREQ;
        for (int k = ls; k < FREQ; k += 256) {
            const float f = (k == 0 || k == FREQ - 1) ? 1.0f : 2.0f;
            s_fr[jj][k] = valid ? re[base + k] * f : 0.0f;
            s_fi[jj][k] = valid ? im[base + k] * f : 0.0f;
        }
    }
    __syncthreads();
    const float* wr = Wr + ls;
    const float* wi = Wi + ls;
    float acc = 0.0f;
    for (int k = 0; k < FREQ; ++k) {
        const float* wrk = wr + (size_t)k * 1024;
        const float* wik = wi + (size_t)k * 1024;
#pragma unroll
        for (int jj = 0; jj < 4; ++jj) {
            acc = fmaf(wrk[jj * 256], s_fr[jj][k], acc);
            acc = fmaf(-wik[jj * 256], s_fi[jj][k], acc);
        }
    }
    float wsv = 0.0f;
#pragma unroll
    for (int jj = 0; jj < 4; ++jj) {
        const int t = g - jj;
        if (t >= 0 && t < NFRAMES) wsv += ola[ls + jj * 256];
    }
    wsv = fmaxf(wsv, 1e-11f);
    out[(size_t)b * OUTCOLS + (g * 256 + ls - 512)] = acc / wsv;
}

extern "C" void kernel_launch(void* const* d_in, const int* in_sizes, int n_in,
                              void* d_out, int out_size, void* d_ws, size_t ws_size,
                              hipStream_t stream) {
    const float* re  = (const float*)d_in[0];
    const float* im  = (const float*)d_in[1];
    const float* Wr  = (const float*)d_in[2];
    const float* Wi  = (const float*)d_in[3];
    const float* ola = (const float*)d_in[4];
    float* out = (float*)d_out;

    if (ws_size >= WS_NEED) {
        unsigned short* frames = (unsigned short*)d_ws;
        hipLaunchKernelGGL(ifft_frames, dim3(16384), dim3(256), 0, stream,
                           re, im, ola, frames);
        hipLaunchKernelGGL(ola_fold, dim3(2047, BATCH), dim3(256), 0, stream,
                           frames, ola, out);
    } else {
        dim3 grid(2047, BATCH);
        hipLaunchKernelGGL(istft_naive, grid, dim3(256), 0, stream,
                           re, im, Wr, Wi, ola, out);
    }
}

// Round 10
// 56.763 us; speedup vs baseline: 3.6014x; 1.2501x over previous
//
#include <hip/hip_runtime.h>

// ISTFT via FFT, two-frames-per-transform pack:
//   frames[b,t,n] = Re{ sum_k X_t[k] e^{+2pi i kn/1024} } * hann[n]/1024
// Pack Z[k] = X_{2m}[k] + i*X_{2m+1}[k]  ->  one 1024-pt complex inverse FFT
// gives frame 2m = Re z, frame 2m+1 = Im z.
// CRITICAL: im[k=0] and im[k=512] are nonzero in the input but contribute 0 to
// the reference (sin(0)=0; Re{i*b*(-1)^n}=0). They must be ZEROED when packing,
// else Im z1 leaks into frame 2 and Im z2 into frame 1 (~|b|/1024 ~ 5e-3 —
// round 9's failure). With b=0 at DC/Nyquist, X1/X2 are exactly Hermitian.
// Kernel 0: twiddle table e^{+2pi i k/1024} -> ws (8KB).
// Kernel 1: radix-4 Stockham 1024-pt IFFT per frame-PAIR (8192 blocks).
// Kernel 2: OLA gather + wsum normalize + crop (proven round-1 logic).

#define BATCH    8
#define NFRAMES  2048
#define FREQ     513
#define OUTCOLS  524032
#define FRAMES_B ((size_t)16384 * 1024 * 2)    // 32 MB bf16 frames
#define TW_OFF   FRAMES_B
#define WS_NEED  (FRAMES_B + 1024 * 8)

#define PD(a) ((a) + ((a) >> 5))               // +1 float pad per 32 (bank spread)

typedef __attribute__((ext_vector_type(2))) float f32x2;

__device__ __forceinline__ unsigned short f2bf(float x) {
    unsigned u = __float_as_uint(x);
    return (unsigned short)((u + 0x7fffu + ((u >> 16) & 1u)) >> 16);
}

// ================= kernel 0: twiddle table =================
__global__ __launch_bounds__(256) void twiddle_prep(float* __restrict__ tw) {
    int k = blockIdx.x * 256 + threadIdx.x;    // 0..1023
    float s, c;
    sincosf(6.283185307179586f * (float)k * (1.0f / 1024.0f), &s, &c);
    ((f32x2*)tw)[k] = (f32x2){c, s};
}

// ================= kernel 1: 1024-pt IFFT per frame-pair =================
__global__ __launch_bounds__(256) void ifft_frames2(
    const float* __restrict__ re, const float* __restrict__ im,
    const float* __restrict__ ola, const float* __restrict__ twg,
    unsigned short* __restrict__ frames) {
    __shared__ float xr[1056], xi[1056], yr[1056], yi[1056];
    __shared__ float twr[1024], twi[1024];

    const int blk = blockIdx.x;        // b*1024 + m  -> rows 2*blk, 2*blk+1
    const int r0  = blk * 2;
    const int tid = threadIdx.x;

    // twiddle table from global (computed once by twiddle_prep)
    for (int k = tid; k < 1024; k += 256) {
        f32x2 t = ((const f32x2*)twg)[k];
        twr[k] = t[0]; twi[k] = t[1];
    }

    // Z[k] = X1[k] + i X2[k]; mirrors from hermitian X1, X2:
    //   k=0..512:   Z[k]      = (a1 - b2) + i(b1 + a2)
    //   k=1..511:   Z[1024-k] = (a1 + b2) + i(a2 - b1)
    // b1 = b2 = 0 forced at k=0 and k=512 (see header comment).
    const float* fre0 = re + (size_t)r0 * FREQ;
    const float* fim0 = im + (size_t)r0 * FREQ;
    const float* fre1 = fre0 + FREQ;
    const float* fim1 = fim0 + FREQ;
#pragma unroll
    for (int h = 0; h < 2; ++h) {
        int k = tid + 256 * h;
        float a1 = fre0[k], b1 = fim0[k];
        float a2 = fre1[k], b2 = fim1[k];
        if (k == 0) { b1 = 0.0f; b2 = 0.0f; }   // DC: imag contributes 0 to ref
        xr[PD(k)] = a1 - b2;
        xi[PD(k)] = b1 + a2;
        if (k > 0) {
            xr[PD(1024 - k)] = a1 + b2;
            xi[PD(1024 - k)] = a2 - b1;
        }
    }
    if (tid == 0) {
        float a1 = fre0[512];
        float a2 = fre1[512];
        xr[PD(512)] = a1;      // Nyquist: b1 = b2 = 0 forced
        xi[PD(512)] = a2;
    }
    __syncthreads();

    // radix-4 DIF Stockham, inverse sign (+i twiddles, +i DFT4) — round-8 proven.
#define STAGE(S, RR, RI, WR, WI)                                              \
    {                                                                         \
        const int p  = tid / (S);                                             \
        const int q  = tid % (S);                                             \
        float ar = RR[PD(tid)],       ai = RI[PD(tid)];                       \
        float br = RR[PD(tid + 256)], bi = RI[PD(tid + 256)];                 \
        float cr = RR[PD(tid + 512)], ci = RI[PD(tid + 512)];                 \
        float dr = RR[PD(tid + 768)], di = RI[PD(tid + 768)];                 \
        float apcr = ar + cr, apci = ai + ci;                                 \
        float amcr = ar - cr, amci = ai - ci;                                 \
        float bpdr = br + dr, bpdi = bi + di;                                 \
        float jbr  = -(bi - di), jbi = (br - dr);   /* i*(b-d) */             \
        const int t1 = p * (S);                                               \
        float w1r = twr[t1],     w1i = twi[t1];                               \
        float w2r = twr[2 * t1], w2i = twi[2 * t1];                           \
        float w3r = twr[3 * t1], w3i = twi[3 * t1];                           \
        const int wb = 4 * (S) * p + q;                                       \
        WR[PD(wb)] = apcr + bpdr;  WI[PD(wb)] = apci + bpdi;                  \
        float u1r = amcr + jbr, u1i = amci + jbi;                             \
        WR[PD(wb + (S))]     = u1r * w1r - u1i * w1i;                         \
        WI[PD(wb + (S))]     = u1r * w1i + u1i * w1r;                         \
        float u2r = apcr - bpdr, u2i = apci - bpdi;                           \
        WR[PD(wb + 2 * (S))] = u2r * w2r - u2i * w2i;                         \
        WI[PD(wb + 2 * (S))] = u2r * w2i + u2i * w2r;                         \
        float u3r = amcr - jbr, u3i = amci - jbi;                             \
        WR[PD(wb + 3 * (S))] = u3r * w3r - u3i * w3i;                         \
        WI[PD(wb + 3 * (S))] = u3r * w3i + u3i * w3r;                         \
        __syncthreads();                                                      \
    }

    STAGE(1,   xr, xi, yr, yi)   // n = 1024
    STAGE(4,   yr, yi, xr, xi)   // n = 256
    STAGE(16,  xr, xi, yr, yi)   // n = 64
    STAGE(64,  yr, yi, xr, xi)   // n = 16
    STAGE(256, xr, xi, yr, yi)   // n = 4   -> result in (yr, yi)
#undef STAGE

    // frame r0 = Re z * hann/1024, frame r0+1 = Im z * hann/1024 (hann = sqrt(ola))
    const float inv = 1.0f / 1024.0f;
    unsigned* f0 = (unsigned*)frames + (size_t)r0 * 512;
    unsigned* f1 = f0 + 512;
#pragma unroll
    for (int h = 0; h < 2; ++h) {
        int n = 2 * tid + 512 * h;
        f32x2 o = *(const f32x2*)(ola + n);
        float s0 = sqrtf(o[0]) * inv, s1 = sqrtf(o[1]) * inv;
        f0[tid + 256 * h] = (unsigned)f2bf(yr[PD(n)] * s0) | ((unsigned)f2bf(yr[PD(n + 1)] * s1) << 16);
        f1[tid + 256 * h] = (unsigned)f2bf(yi[PD(n)] * s0) | ((unsigned)f2bf(yi[PD(n + 1)] * s1) << 16);
    }
}

// ================= kernel 2: OLA gather + wsum normalize =================
__global__ __launch_bounds__(256) void ola_fold(
    const unsigned short* __restrict__ frames, const float* __restrict__ ola,
    float* __restrict__ out) {
    const int g  = blockIdx.x + 2;   // 2..2048
    const int b  = blockIdx.y;
    const int ls = threadIdx.x;

    float acc = 0.0f, wsv = 0.0f;
#pragma unroll
    for (int j = 0; j < 4; ++j) {
        const int t = g - j;
        if (t >= 0 && t < NFRAMES) {
            unsigned short h = frames[((size_t)(b * NFRAMES + t) << 10) + ls + 256 * j];
            acc += __uint_as_float(((unsigned)h) << 16);
            wsv += ola[ls + 256 * j];
        }
    }
    wsv = fmaxf(wsv, 1e-11f);
    out[(size_t)b * OUTCOLS + (g * 256 + ls - 512)] = acc / wsv;
}

// ================= last-resort naive fallback (round-1, proven) =================
__global__ __launch_bounds__(256) void istft_naive(
    const float* __restrict__ re, const float* __restrict__ im,
    const float* __restrict__ Wr, const float* __restrict__ Wi,
    const float* __restrict__ ola, float* __restrict__ out) {
    const int g = blockIdx.x + 2, b = blockIdx.y, ls = threadIdx.x;
    __shared__ float s_fr[4][FREQ];
    __shared__ float s_fi[4][FREQ];
#pragma unroll
    for (int jj = 0; jj < 4; ++jj) {
        const int t = g - jj;
        const bool valid = (t >= 0 && t < NFRAMES);
        const size_t base = ((size_t)b * NFRAMES + (valid ? t : 0)) * FREQ;
        for (int k = ls; k < FREQ; k += 256) {
            const float f = (k == 0 || k == FREQ - 1) ? 1.0f : 2.0f;
            s_fr[jj][k] = valid ? re[base + k] * f : 0.0f;
            s_fi[jj][k] = valid ? im[base + k] * f : 0.0f;
        }
    }
    __syncthreads();
    const float* wr = Wr + ls;
    const float* wi = Wi + ls;
    float acc = 0.0f;
    for (int k = 0; k < FREQ; ++k) {
        const float* wrk = wr + (size_t)k * 1024;
        const float* wik = wi + (size_t)k * 1024;
#pragma unroll
        for (int jj = 0; jj < 4; ++jj) {
            acc = fmaf(wrk[jj * 256], s_fr[jj][k], acc);
            acc = fmaf(-wik[jj * 256], s_fi[jj][k], acc);
        }
    }
    float wsv = 0.0f;
#pragma unroll
    for (int jj = 0; jj < 4; ++jj) {
        const int t = g - jj;
        if (t >= 0 && t < NFRAMES) wsv += ola[ls + jj * 256];
    }
    wsv = fmaxf(wsv, 1e-11f);
    out[(size_t)b * OUTCOLS + (g * 256 + ls - 512)] = acc / wsv;
}

extern "C" void kernel_launch(void* const* d_in, const int* in_sizes, int n_in,
                              void* d_out, int out_size, void* d_ws, size_t ws_size,
                              hipStream_t stream) {
    const float* re  = (const float*)d_in[0];
    const float* im  = (const float*)d_in[1];
    const float* Wr  = (const float*)d_in[2];
    const float* Wi  = (const float*)d_in[3];
    const float* ola = (const float*)d_in[4];
    float* out = (float*)d_out;

    if (ws_size >= WS_NEED) {
        unsigned short* frames = (unsigned short*)d_ws;
        float* tw = (float*)((char*)d_ws + TW_OFF);
        hipLaunchKernelGGL(twiddle_prep, dim3(4), dim3(256), 0, stream, tw);
        hipLaunchKernelGGL(ifft_frames2, dim3(8192), dim3(256), 0, stream,
                           re, im, ola, tw, frames);
        hipLaunchKernelGGL(ola_fold, dim3(2047, BATCH), dim3(256), 0, stream,
                           frames, ola, out);
    } else {
        dim3 grid(2047, BATCH);
        hipLaunchKernelGGL(istft_naive, grid, dim3(256), 0, stream,
                           re, im, Wr, Wi, ola, out);
    }
}

// Round 12
// 46.193 us; speedup vs baseline: 4.4255x; 1.2288x over previous
//
#include <hip/hip_runtime.h>

// ISTFT via FFT, two-frames-per-transform pack:
//   frames[b,t,n] = Re{ sum_k X_t[k] e^{+2pi i kn/1024} } * hann[n]/1024
// Pack Z[k] = X_{2m}[k] + i*X_{2m+1}[k]  ->  one 1024-pt complex inverse FFT
// gives frame 2m = Re z, frame 2m+1 = Im z.
// im[k=0] and im[k=512] are ZEROED when packing: they contribute 0 to the
// reference (sin(0)=0; Re{i*b*(-1)^n}=0) but would leak across the pack.
// Kernel 0: twiddle table e^{+2pi i k/1024} -> ws (8KB, f32x2).
// Kernel 1: radix-4 Stockham 1024-pt IFFT per frame-PAIR (8192 blocks),
//           complex in LDS as float2, twiddles from L1, no-twiddle last stage.
//           NOTE: last stage (S=256, p=0) writes out[tid + 256*k] — the generic
//           Stockham rule out[4Sp+q+Sk]; round 11 wrote 4*tid+k (wrong perm).
// Kernel 2: OLA gather, 2 samples/thread (u32 frame loads), wsum norm, crop.

#define BATCH    8
#define NFRAMES  2048
#define FREQ     513
#define OUTCOLS  524032
#define FRAMES_B ((size_t)16384 * 1024 * 2)    // 32 MB bf16 frames
#define TW_OFF   FRAMES_B
#define WS_NEED  (FRAMES_B + 1024 * 8)

#define PD(a) ((a) + ((a) >> 4))               // pad 1 f32x2 per 16

typedef __attribute__((ext_vector_type(2))) float f32x2;

__device__ __forceinline__ unsigned short f2bf(float x) {
    unsigned u = __float_as_uint(x);
    return (unsigned short)((u + 0x7fffu + ((u >> 16) & 1u)) >> 16);
}

// ================= kernel 0: twiddle table =================
__global__ __launch_bounds__(256) void twiddle_prep(float* __restrict__ tw) {
    int k = blockIdx.x * 256 + threadIdx.x;    // 0..1023
    float s, c;
    sincosf(6.283185307179586f * (float)k * (1.0f / 1024.0f), &s, &c);
    ((f32x2*)tw)[k] = (f32x2){c, s};
}

// ================= kernel 1: 1024-pt IFFT per frame-pair =================
__global__ __launch_bounds__(256) void ifft_frames3(
    const float* __restrict__ re, const float* __restrict__ im,
    const float* __restrict__ ola, const float* __restrict__ twg,
    unsigned short* __restrict__ frames) {
    __shared__ f32x2 X[1088], Y[1088];         // PD16-padded 1024-complex

    const int blk = blockIdx.x;        // b*1024 + m  -> rows 2*blk, 2*blk+1
    const int r0  = blk * 2;
    const int tid = threadIdx.x;
    const f32x2* tw = (const f32x2*)twg;

    // Z[k] = X1[k] + i X2[k]; mirrors from hermitian X1, X2:
    //   k=0..512:   Z[k]      = (a1 - b2) + i(b1 + a2)
    //   k=1..511:   Z[1024-k] = (a1 + b2) + i(a2 - b1)
    const float* fre0 = re + (size_t)r0 * FREQ;
    const float* fim0 = im + (size_t)r0 * FREQ;
    const float* fre1 = fre0 + FREQ;
    const float* fim1 = fim0 + FREQ;
#pragma unroll
    for (int h = 0; h < 2; ++h) {
        int k = tid + 256 * h;
        float a1 = fre0[k], b1 = fim0[k];
        float a2 = fre1[k], b2 = fim1[k];
        if (k == 0) { b1 = 0.0f; b2 = 0.0f; }   // DC imag contributes 0 to ref
        X[PD(k)] = (f32x2){a1 - b2, b1 + a2};
        if (k > 0) X[PD(1024 - k)] = (f32x2){a1 + b2, a2 - b1};
    }
    if (tid == 0)
        X[PD(512)] = (f32x2){fre0[512], fre1[512]};  // Nyquist imag zeroed
    __syncthreads();

    // radix-4 DIF Stockham, inverse sign (+i twiddles, +i DFT4).
#define STAGE(S, RB, WB)                                                      \
    {                                                                         \
        const int p  = tid / (S);                                             \
        const int q  = tid % (S);                                             \
        f32x2 a = RB[PD(tid)];                                                \
        f32x2 b = RB[PD(tid + 256)];                                          \
        f32x2 c = RB[PD(tid + 512)];                                          \
        f32x2 d = RB[PD(tid + 768)];                                          \
        float apcr = a[0] + c[0], apci = a[1] + c[1];                         \
        float amcr = a[0] - c[0], amci = a[1] - c[1];                         \
        float bpdr = b[0] + d[0], bpdi = b[1] + d[1];                         \
        float jbr  = -(b[1] - d[1]), jbi = (b[0] - d[0]);   /* i*(b-d) */     \
        const int t1 = p * (S);                                               \
        f32x2 w1 = tw[t1], w2 = tw[2 * t1], w3 = tw[3 * t1];                  \
        const int wb = 4 * (S) * p + q;                                       \
        WB[PD(wb)] = (f32x2){apcr + bpdr, apci + bpdi};                       \
        float u1r = amcr + jbr, u1i = amci + jbi;                             \
        WB[PD(wb + (S))]     = (f32x2){u1r * w1[0] - u1i * w1[1],             \
                                       u1r * w1[1] + u1i * w1[0]};            \
        float u2r = apcr - bpdr, u2i = apci - bpdi;                           \
        WB[PD(wb + 2 * (S))] = (f32x2){u2r * w2[0] - u2i * w2[1],             \
                                       u2r * w2[1] + u2i * w2[0]};            \
        float u3r = amcr - jbr, u3i = amci - jbi;                             \
        WB[PD(wb + 3 * (S))] = (f32x2){u3r * w3[0] - u3i * w3[1],             \
                                       u3r * w3[1] + u3i * w3[0]};            \
        __syncthreads();                                                      \
    }

    STAGE(1,  X, Y)    // n = 1024
    STAGE(4,  Y, X)    // n = 256
    STAGE(16, X, Y)    // n = 64
    STAGE(64, Y, X)    // n = 16
    {  // S = 256: p = 0, q = tid -> twiddles all 1; writes out[tid + 256*k]
        f32x2 a = X[PD(tid)];
        f32x2 b = X[PD(tid + 256)];
        f32x2 c = X[PD(tid + 512)];
        f32x2 d = X[PD(tid + 768)];
        float apcr = a[0] + c[0], apci = a[1] + c[1];
        float amcr = a[0] - c[0], amci = a[1] - c[1];
        float bpdr = b[0] + d[0], bpdi = b[1] + d[1];
        float jbr  = -(b[1] - d[1]), jbi = (b[0] - d[0]);
        Y[PD(tid)]       = (f32x2){apcr + bpdr, apci + bpdi};
        Y[PD(tid + 256)] = (f32x2){amcr + jbr, amci + jbi};
        Y[PD(tid + 512)] = (f32x2){apcr - bpdr, apci - bpdi};
        Y[PD(tid + 768)] = (f32x2){amcr - jbr, amci - jbi};
        __syncthreads();
    }
#undef STAGE

    // frame r0 = Re z * hann/1024, frame r0+1 = Im z * hann/1024 (hann=sqrt(ola))
    const float inv = 1.0f / 1024.0f;
    unsigned* f0 = (unsigned*)frames + (size_t)r0 * 512;
    unsigned* f1 = f0 + 512;
#pragma unroll
    for (int h = 0; h < 2; ++h) {
        int n = 2 * tid + 512 * h;
        f32x2 o  = *(const f32x2*)(ola + n);
        float s0 = sqrtf(o[0]) * inv, s1 = sqrtf(o[1]) * inv;
        f32x2 z0 = Y[PD(n)], z1 = Y[PD(n + 1)];
        f0[tid + 256 * h] = (unsigned)f2bf(z0[0] * s0) | ((unsigned)f2bf(z1[0] * s1) << 16);
        f1[tid + 256 * h] = (unsigned)f2bf(z0[1] * s0) | ((unsigned)f2bf(z1[1] * s1) << 16);
    }
}

// ================= kernel 2: OLA gather, 2 samples/thread =================
__global__ __launch_bounds__(256) void ola_fold2(
    const unsigned short* __restrict__ frames, const float* __restrict__ ola,
    float* __restrict__ out) {
    const int col0 = (blockIdx.x * 256 + threadIdx.x) * 2;
    if (col0 >= OUTCOLS) return;
    const int b  = blockIdx.y;
    const int s  = col0 + 512;     // uncropped sample index
    const int g  = s >> 8;
    const int ls = s & 255;        // even

    float acc0 = 0.0f, acc1 = 0.0f, ws0 = 0.0f, ws1 = 0.0f;
#pragma unroll
    for (int j = 0; j < 4; ++j) {
        const int t = g - j;
        if (t >= 0 && t < NFRAMES) {
            unsigned u = *(const unsigned*)(frames + ((size_t)(b * NFRAMES + t) << 10) + ls + 256 * j);
            acc0 += __uint_as_float(u << 16);
            acc1 += __uint_as_float(u & 0xffff0000u);
            f32x2 o = *(const f32x2*)(ola + ls + 256 * j);
            ws0 += o[0];
            ws1 += o[1];
        }
    }
    ws0 = fmaxf(ws0, 1e-11f);
    ws1 = fmaxf(ws1, 1e-11f);
    *(f32x2*)(out + (size_t)b * OUTCOLS + col0) = (f32x2){acc0 / ws0, acc1 / ws1};
}

// ================= last-resort naive fallback (round-1, proven) =================
__global__ __launch_bounds__(256) void istft_naive(
    const float* __restrict__ re, const float* __restrict__ im,
    const float* __restrict__ Wr, const float* __restrict__ Wi,
    const float* __restrict__ ola, float* __restrict__ out) {
    const int g = blockIdx.x + 2, b = blockIdx.y, ls = threadIdx.x;
    __shared__ float s_fr[4][FREQ];
    __shared__ float s_fi[4][FREQ];
#pragma unroll
    for (int jj = 0; jj < 4; ++jj) {
        const int t = g - jj;
        const bool valid = (t >= 0 && t < NFRAMES);
        const size_t base = ((size_t)b * NFRAMES + (valid ? t : 0)) * FREQ;
        for (int k = ls; k < FREQ; k += 256) {
            const float f = (k == 0 || k == FREQ - 1) ? 1.0f : 2.0f;
            s_fr[jj][k] = valid ? re[base + k] * f : 0.0f;
            s_fi[jj][k] = valid ? im[base + k] * f : 0.0f;
        }
    }
    __syncthreads();
    const float* wr = Wr + ls;
    const float* wi = Wi + ls;
    float acc = 0.0f;
    for (int k = 0; k < FREQ; ++k) {
        const float* wrk = wr + (size_t)k * 1024;
        const float* wik = wi + (size_t)k * 1024;
#pragma unroll
        for (int jj = 0; jj < 4; ++jj) {
            acc = fmaf(wrk[jj * 256], s_fr[jj][k], acc);
            acc = fmaf(-wik[jj * 256], s_fi[jj][k], acc);
        }
    }
    float wsv = 0.0f;
#pragma unroll
    for (int jj = 0; jj < 4; ++jj) {
        const int t = g - jj;
        if (t >= 0 && t < NFRAMES) wsv += ola[ls + jj * 256];
    }
    wsv = fmaxf(wsv, 1e-11f);
    out[(size_t)b * OUTCOLS + (g * 256 + ls - 512)] = acc / wsv;
}

extern "C" void kernel_launch(void* const* d_in, const int* in_sizes, int n_in,
                              void* d_out, int out_size, void* d_ws, size_t ws_size,
                              hipStream_t stream) {
    const float* re  = (const float*)d_in[0];
    const float* im  = (const float*)d_in[1];
    const float* Wr  = (const float*)d_in[2];
    const float* Wi  = (const float*)d_in[3];
    const float* ola = (const float*)d_in[4];
    float* out = (float*)d_out;

    if (ws_size >= WS_NEED) {
        unsigned short* frames = (unsigned short*)d_ws;
        float* tw = (float*)((char*)d_ws + TW_OFF);
        hipLaunchKernelGGL(twiddle_prep, dim3(4), dim3(256), 0, stream, tw);
        hipLaunchKernelGGL(ifft_frames3, dim3(8192), dim3(256), 0, stream,
                           re, im, ola, tw, frames);
        hipLaunchKernelGGL(ola_fold2, dim3(1024, BATCH), dim3(256), 0, stream,
                           frames, ola, out);
    } else {
        dim3 grid(2047, BATCH);
        hipLaunchKernelGGL(istft_naive, grid, dim3(256), 0, stream,
                           re, im, Wr, Wi, ola, out);
    }
}